// Round 3
// baseline (669.330 us; speedup 1.0000x reference)
//
#include <hip/hip_runtime.h>

#define N_NODES  100000
#define N_EDGES  1600000
#define NODE_DIM 64
#define HID      32
#define NUM_LAYERS 3
#define SCAN_B   1024   // elements per scan1 block

// 8 nodes per 256-thread block (32 lanes per node, 2 nodes per wave64)
#define NPB 8
#define GRIDG (N_NODES / NPB)   // 12500, exact

// ------------------------------- sort: CSR by dst ---------------------------
__global__ void zero_int_kernel(int* __restrict__ p, int n) {
    int i = blockIdx.x * blockDim.x + threadIdx.x;
    if (i < n) p[i] = 0;
}

__global__ void rank_kernel(const int* __restrict__ ei,
                            int* __restrict__ cnt, int* __restrict__ rank) {
    int e = blockIdx.x * blockDim.x + threadIdx.x;
    if (e >= N_EDGES) return;
    int d = ei[N_EDGES + e];
    rank[e] = atomicAdd(&cnt[d], 1);
}

// scan1: per-block exclusive scan of cnt (1024 elems/block of 256 threads)
__global__ void scan1_kernel(const int* __restrict__ cnt, int* __restrict__ off,
                             int* __restrict__ bsum) {
    __shared__ int lds[256];
    int tid = threadIdx.x;
    int base = blockIdx.x * SCAN_B + tid * 4;
    int v0 = (base + 0 < N_NODES) ? cnt[base + 0] : 0;
    int v1 = (base + 1 < N_NODES) ? cnt[base + 1] : 0;
    int v2 = (base + 2 < N_NODES) ? cnt[base + 2] : 0;
    int v3 = (base + 3 < N_NODES) ? cnt[base + 3] : 0;
    int s1 = v0, s2 = v0 + v1, s3 = v0 + v1 + v2;
    int tsum = s3 + v3;
    lds[tid] = tsum;
    __syncthreads();
    for (int d = 1; d < 256; d <<= 1) {
        int t = lds[tid];
        int u = (tid >= d) ? lds[tid - d] : 0;
        __syncthreads();
        lds[tid] = t + u;
        __syncthreads();
    }
    int excl = lds[tid] - tsum;
    if (base + 0 < N_NODES) off[base + 0] = excl;
    if (base + 1 < N_NODES) off[base + 1] = excl + s1;
    if (base + 2 < N_NODES) off[base + 2] = excl + s2;
    if (base + 3 < N_NODES) off[base + 3] = excl + s3;
    if (tid == 255) bsum[blockIdx.x] = lds[255];
}

__global__ void scan2_kernel(const int* __restrict__ bsum, int* __restrict__ boff, int nb) {
    __shared__ int lds[256];
    int tid = threadIdx.x;
    int v = (tid < nb) ? bsum[tid] : 0;
    lds[tid] = v;
    __syncthreads();
    for (int d = 1; d < 256; d <<= 1) {
        int t = lds[tid];
        int u = (tid >= d) ? lds[tid - d] : 0;
        __syncthreads();
        lds[tid] = t + u;
        __syncthreads();
    }
    if (tid < nb) boff[tid] = lds[tid] - v;
}

__global__ void scan3_kernel(int* __restrict__ off, const int* __restrict__ boff) {
    int i = blockIdx.x * blockDim.x + threadIdx.x;
    if (i < N_NODES) off[i] += boff[i / SCAN_B];
}

// scatter: ONE packed 8B store per edge (src id + dist bits) into dst-sorted order
__global__ void scatter_kernel(const int* __restrict__ ei,
                               const float* __restrict__ pos,
                               const int* __restrict__ off,
                               const int* __restrict__ rank,
                               int2* __restrict__ recs) {
    int e = blockIdx.x * blockDim.x + threadIdx.x;
    if (e >= N_EDGES) return;
    int s = ei[e];
    int d = ei[N_EDGES + e];
    float dx = pos[d * 3 + 0] - pos[s * 3 + 0];
    float dy = pos[d * 3 + 1] - pos[s * 3 + 1];
    float dz = pos[d * 3 + 2] - pos[s * 3 + 2];
    int t = off[d] + rank[e];
    recs[t] = make_int2(s, __float_as_int(sqrtf(dx * dx + dy * dy + dz * dz)));
}

// ------------------------------- model kernels ------------------------------
// All model kernels: 32 lanes per node, lane j owns output channel j.
// Matmuls done as shuffle-broadcast outer products within the 32-lane group.

__global__ void encoder_kernel(const float* __restrict__ feat,
                               const float* __restrict__ w1, const float* __restrict__ b1,
                               const float* __restrict__ w2, const float* __restrict__ b2,
                               float* __restrict__ xout) {
    int j = threadIdx.x & 31;
    int n = blockIdx.x * NPB + (threadIdx.x >> 5);
    float f0 = feat[(size_t)n * NODE_DIM + j];
    float f1 = feat[(size_t)n * NODE_DIM + 32 + j];
    float hj = b1[j];
#pragma unroll
    for (int k = 0; k < 32; ++k) {
        float fk = __shfl(f0, k, 32);
        hj = fmaf(fk, w1[k * HID + j], hj);
    }
#pragma unroll
    for (int k = 0; k < 32; ++k) {
        float fk = __shfl(f1, k, 32);
        hj = fmaf(fk, w1[(32 + k) * HID + j], hj);
    }
    hj = fmaxf(hj, 0.0f);
    float yj = b2[j];
#pragma unroll
    for (int k = 0; k < 32; ++k) {
        float hk = __shfl(hj, k, 32);
        yj = fmaf(hk, w2[k * HID + j], yj);
    }
    xout[(size_t)n * HID + j] = yj;
}

// per-layer node projections: p = x @ W1[0:32] + b1 (dst half), q = x @ W1[32:64] (src half)
__global__ void proj_kernel(const float* __restrict__ x,
                            const float* __restrict__ w1, const float* __restrict__ b1,
                            float* __restrict__ p, float* __restrict__ q) {
    int j = threadIdx.x & 31;
    int n = blockIdx.x * NPB + (threadIdx.x >> 5);
    float xj = x[(size_t)n * HID + j];
    float pp = b1[j];
    float qq = 0.0f;
#pragma unroll
    for (int k = 0; k < 32; ++k) {
        float xk = __shfl(xj, k, 32);
        pp = fmaf(xk, w1[k * HID + j], pp);
        qq = fmaf(xk, w1[(HID + k) * HID + j], qq);
    }
    p[(size_t)n * HID + j] = pp;
    q[(size_t)n * HID + j] = qq;
}

// fused: CSR gather + relu-accum + (@W2 + deg*b2) + update MLP, in-place x
__global__ void gather_update_kernel(float* __restrict__ x,
                                     const float* __restrict__ p,
                                     const float* __restrict__ q,
                                     const int2* __restrict__ recs,
                                     const int* __restrict__ off,
                                     const float* __restrict__ w1,   // for dist row (row 64)
                                     const float* __restrict__ w2,
                                     const float* __restrict__ b2,
                                     const float* __restrict__ uw1, const float* __restrict__ ub1,
                                     const float* __restrict__ uw2, const float* __restrict__ ub2) {
    int j = threadIdx.x & 31;
    int n = blockIdx.x * NPB + (threadIdx.x >> 5);
    int t0 = off[n];
    int t1 = (n == N_NODES - 1) ? N_EDGES : off[n + 1];

    float ppj = p[(size_t)n * HID + j];
    float wdj = w1[2 * HID * HID + j];   // dist row
    float rsum = 0.0f;

    for (int t = t0; t < t1; t += 32) {
        int m = t1 - t; if (m > 32) m = 32;   // uniform within the 32-lane group
        int2 rec = (j < m) ? recs[t + j] : make_int2(0, 0);
#pragma unroll 8
        for (int k = 0; k < m; ++k) {
            int   s  = __shfl(rec.x, k, 32);
            float dt = __int_as_float(__shfl(rec.y, k, 32));
            float qv = q[(size_t)s * HID + j];          // coalesced 128B row
            rsum += fmaxf(fmaf(dt, wdj, ppj + qv), 0.0f);
        }
    }

    // agg = rsum @ W2 + deg * b2
    float deg = (float)(t1 - t0);
    float aggj = deg * b2[j];
#pragma unroll
    for (int k = 0; k < HID; ++k) {
        float rk = __shfl(rsum, k, 32);
        aggj = fmaf(rk, w2[k * HID + j], aggj);
    }

    // update MLP: h = relu([x, agg] @ uw1 + ub1); y = h @ uw2 + ub2
    float xj = x[(size_t)n * HID + j];
    float hj = ub1[j];
#pragma unroll
    for (int k = 0; k < HID; ++k) {
        float xk = __shfl(xj, k, 32);
        hj = fmaf(xk, uw1[k * HID + j], hj);
    }
#pragma unroll
    for (int k = 0; k < HID; ++k) {
        float ak = __shfl(aggj, k, 32);
        hj = fmaf(ak, uw1[(HID + k) * HID + j], hj);
    }
    hj = fmaxf(hj, 0.0f);
    float yj = ub2[j];
#pragma unroll
    for (int k = 0; k < HID; ++k) {
        float hk = __shfl(hj, k, 32);
        yj = fmaf(hk, uw2[k * HID + j], yj);
    }
    x[(size_t)n * HID + j] = yj;
}

__global__ void out_kernel(const float* __restrict__ x,
                           const float* __restrict__ w, const float* __restrict__ b,
                           float* __restrict__ out) {
    int j = threadIdx.x & 31;
    int n = blockIdx.x * NPB + (threadIdx.x >> 5);
    float xj = x[(size_t)n * HID + j];
    float yj = b[j];
#pragma unroll
    for (int k = 0; k < 32; ++k) {
        float xk = __shfl(xj, k, 32);
        yj = fmaf(xk, w[k * HID + j], yj);
    }
    out[(size_t)n * HID + j] = yj;
}

// ---------------------------------------------------------------------------
extern "C" void kernel_launch(void* const* d_in, const int* in_sizes, int n_in,
                              void* d_out, int out_size, void* d_ws, size_t ws_size,
                              hipStream_t stream) {
    const float* node_feat = (const float*)d_in[0];
    const float* pos       = (const float*)d_in[1];
    const int*   ei        = (const int*)  d_in[2];   // int32 on device
    const float* enc_w1    = (const float*)d_in[3];
    const float* enc_b1    = (const float*)d_in[4];
    const float* enc_w2    = (const float*)d_in[5];
    const float* enc_b2    = (const float*)d_in[6];
    const float* msg_w1    = (const float*)d_in[7];   // [3, 65, 32]
    const float* msg_b1    = (const float*)d_in[8];
    const float* msg_w2    = (const float*)d_in[9];   // [3, 32, 32]
    const float* msg_b2    = (const float*)d_in[10];
    const float* upd_w1    = (const float*)d_in[11];  // [3, 64, 32]
    const float* upd_b1    = (const float*)d_in[12];
    const float* upd_w2    = (const float*)d_in[13];
    const float* upd_b2    = (const float*)d_in[14];
    const float* out_w     = (const float*)d_in[15];
    const float* out_b     = (const float*)d_in[16];
    float* out = (float*)d_out;

    // workspace layout (4-byte elements), ~58.4 MB total
    char* ws = (char*)d_ws;
    float* x      = (float*)ws;                                   // N*32
    float* p      = x + (size_t)N_NODES * HID;                    // N*32
    float* q      = p + (size_t)N_NODES * HID;                    // N*32
    int2*  recs   = (int2*)(q + (size_t)N_NODES * HID);           // E (8B each)
    int*   rank   = (int*)(recs + (size_t)N_EDGES);               // E
    int*   cnt    = rank + (size_t)N_EDGES;                       // N
    int*   off    = cnt + N_NODES;                                // N+1 (off[N] unused)
    int*   bsum   = off + (N_NODES + 1);                          // <=256
    int*   boff   = bsum + 256;                                   // <=256

    const int B = 256;
    const int gridE = (N_EDGES + B - 1) / B;
    const int NB = (N_NODES + SCAN_B - 1) / SCAN_B;               // 98

    // ---- build CSR (once per launch) ----
    zero_int_kernel<<<(N_NODES + B - 1) / B, B, 0, stream>>>(cnt, N_NODES);
    rank_kernel<<<gridE, B, 0, stream>>>(ei, cnt, rank);
    scan1_kernel<<<NB, 256, 0, stream>>>(cnt, off, bsum);
    scan2_kernel<<<1, 256, 0, stream>>>(bsum, boff, NB);
    scan3_kernel<<<(N_NODES + B - 1) / B, B, 0, stream>>>(off, boff);
    scatter_kernel<<<gridE, B, 0, stream>>>(ei, pos, off, rank, recs);

    // ---- model (32 lanes per node; 8 nodes per block) ----
    encoder_kernel<<<GRIDG, B, 0, stream>>>(node_feat, enc_w1, enc_b1, enc_w2, enc_b2, x);

    for (int l = 0; l < NUM_LAYERS; ++l) {
        const float* w1 = msg_w1 + (size_t)l * (2 * HID + 1) * HID;
        proj_kernel<<<GRIDG, B, 0, stream>>>(x, w1, msg_b1 + (size_t)l * HID, p, q);
        gather_update_kernel<<<GRIDG, B, 0, stream>>>(
            x, p, q, recs, off,
            w1,
            msg_w2 + (size_t)l * HID * HID,
            msg_b2 + (size_t)l * HID,
            upd_w1 + (size_t)l * (2 * HID) * HID,
            upd_b1 + (size_t)l * HID,
            upd_w2 + (size_t)l * HID * HID,
            upd_b2 + (size_t)l * HID);
    }
    out_kernel<<<GRIDG, B, 0, stream>>>(x, out_w, out_b, out);
}

// Round 4
// 564.269 us; speedup vs baseline: 1.1862x; 1.1862x over previous
//
#include <hip/hip_runtime.h>

#define N_NODES  100000
#define N_EDGES  1600000
#define NODE_DIM 64
#define HID      32
#define NUM_LAYERS 3
#define SCAN_B   1024   // elements per scan1 block

// model kernels: 8 lanes per node; lane r owns channels 4r..4r+3 (float4).
// 256-thread block = 32 nodes; wave64 = 8 nodes.
#define NPB4  32
#define GRID4 (N_NODES / NPB4)   // 3125, exact

// ------------------------------- sort: CSR by dst ---------------------------
__global__ void zero_int_kernel(int* __restrict__ p, int n) {
    int i = blockIdx.x * blockDim.x + threadIdx.x;
    if (i < n) p[i] = 0;
}

__global__ void rank_kernel(const int* __restrict__ ei,
                            int* __restrict__ cnt, int* __restrict__ rank) {
    int e = blockIdx.x * blockDim.x + threadIdx.x;
    if (e >= N_EDGES) return;
    int d = ei[N_EDGES + e];
    rank[e] = atomicAdd(&cnt[d], 1);
}

// scan1: per-block exclusive scan of cnt (1024 elems/block of 256 threads)
__global__ void scan1_kernel(const int* __restrict__ cnt, int* __restrict__ off,
                             int* __restrict__ bsum) {
    __shared__ int lds[256];
    int tid = threadIdx.x;
    int base = blockIdx.x * SCAN_B + tid * 4;
    int v0 = (base + 0 < N_NODES) ? cnt[base + 0] : 0;
    int v1 = (base + 1 < N_NODES) ? cnt[base + 1] : 0;
    int v2 = (base + 2 < N_NODES) ? cnt[base + 2] : 0;
    int v3 = (base + 3 < N_NODES) ? cnt[base + 3] : 0;
    int s1 = v0, s2 = v0 + v1, s3 = v0 + v1 + v2;
    int tsum = s3 + v3;
    lds[tid] = tsum;
    __syncthreads();
    for (int d = 1; d < 256; d <<= 1) {
        int t = lds[tid];
        int u = (tid >= d) ? lds[tid - d] : 0;
        __syncthreads();
        lds[tid] = t + u;
        __syncthreads();
    }
    int excl = lds[tid] - tsum;
    if (base + 0 < N_NODES) off[base + 0] = excl;
    if (base + 1 < N_NODES) off[base + 1] = excl + s1;
    if (base + 2 < N_NODES) off[base + 2] = excl + s2;
    if (base + 3 < N_NODES) off[base + 3] = excl + s3;
    if (tid == 255) bsum[blockIdx.x] = lds[255];
}

__global__ void scan2_kernel(const int* __restrict__ bsum, int* __restrict__ boff, int nb) {
    __shared__ int lds[256];
    int tid = threadIdx.x;
    int v = (tid < nb) ? bsum[tid] : 0;
    lds[tid] = v;
    __syncthreads();
    for (int d = 1; d < 256; d <<= 1) {
        int t = lds[tid];
        int u = (tid >= d) ? lds[tid - d] : 0;
        __syncthreads();
        lds[tid] = t + u;
        __syncthreads();
    }
    if (tid < nb) boff[tid] = lds[tid] - v;
}

__global__ void scan3_kernel(int* __restrict__ off, const int* __restrict__ boff) {
    int i = blockIdx.x * blockDim.x + threadIdx.x;
    if (i < N_NODES) off[i] += boff[i / SCAN_B];
}

// scatter: ONE packed 8B store per edge (src id + dist bits) into dst-sorted order
__global__ void scatter_kernel(const int* __restrict__ ei,
                               const float* __restrict__ pos,
                               const int* __restrict__ off,
                               const int* __restrict__ rank,
                               int2* __restrict__ recs) {
    int e = blockIdx.x * blockDim.x + threadIdx.x;
    if (e >= N_EDGES) return;
    int s = ei[e];
    int d = ei[N_EDGES + e];
    float dx = pos[d * 3 + 0] - pos[s * 3 + 0];
    float dy = pos[d * 3 + 1] - pos[s * 3 + 1];
    float dz = pos[d * 3 + 2] - pos[s * 3 + 2];
    int t = off[d] + rank[e];
    recs[t] = make_int2(s, __float_as_int(sqrtf(dx * dx + dy * dy + dz * dz)));
}

// ------------------------------- model helpers ------------------------------
__device__ __forceinline__ void fma4(float4& acc, float a, const float4 w) {
    acc.x = fmaf(a, w.x, acc.x);
    acc.y = fmaf(a, w.y, acc.y);
    acc.z = fmaf(a, w.z, acc.z);
    acc.w = fmaf(a, w.w, acc.w);
}

// acc += v @ W, where W is 32x32 row-major and v is distributed over an
// 8-lane group (lane r holds channels 4r..4r+3). Each lane produces its
// own 4 output channels.
__device__ __forceinline__ void matvec32(float4 v, const float* __restrict__ w,
                                         int r, float4& acc) {
    const float4* w4 = reinterpret_cast<const float4*>(w);
#pragma unroll
    for (int kk = 0; kk < 8; ++kk) {
        float a0 = __shfl(v.x, kk, 8);
        float a1 = __shfl(v.y, kk, 8);
        float a2 = __shfl(v.z, kk, 8);
        float a3 = __shfl(v.w, kk, 8);
        fma4(acc, a0, w4[(4 * kk + 0) * 8 + r]);
        fma4(acc, a1, w4[(4 * kk + 1) * 8 + r]);
        fma4(acc, a2, w4[(4 * kk + 2) * 8 + r]);
        fma4(acc, a3, w4[(4 * kk + 3) * 8 + r]);
    }
}

__device__ __forceinline__ float4 relu4(float4 v) {
    v.x = fmaxf(v.x, 0.0f); v.y = fmaxf(v.y, 0.0f);
    v.z = fmaxf(v.z, 0.0f); v.w = fmaxf(v.w, 0.0f);
    return v;
}

// ------------------------------- model kernels ------------------------------
__global__ void encoder_kernel(const float* __restrict__ feat,
                               const float* __restrict__ w1, const float* __restrict__ b1,
                               const float* __restrict__ w2, const float* __restrict__ b2,
                               float* __restrict__ xout) {
    int r = threadIdx.x & 7;
    int n = blockIdx.x * NPB4 + (threadIdx.x >> 3);
    const float4* f4 = reinterpret_cast<const float4*>(feat);
    float4 f0 = f4[(size_t)n * 16 + r];        // channels 4r..4r+3
    float4 f1 = f4[(size_t)n * 16 + 8 + r];    // channels 32+4r..32+4r+3
    float4 h = reinterpret_cast<const float4*>(b1)[r];
    matvec32(f0, w1, r, h);
    matvec32(f1, w1 + 32 * HID, r, h);
    h = relu4(h);
    float4 y = reinterpret_cast<const float4*>(b2)[r];
    matvec32(h, w2, r, y);
    reinterpret_cast<float4*>(xout)[(size_t)n * 8 + r] = y;
}

// per-layer node projections: p = x @ W1[0:32] + b1 (dst half), q = x @ W1[32:64] (src half)
__global__ void proj_kernel(const float* __restrict__ x,
                            const float* __restrict__ w1, const float* __restrict__ b1,
                            float* __restrict__ p, float* __restrict__ q) {
    int r = threadIdx.x & 7;
    int n = blockIdx.x * NPB4 + (threadIdx.x >> 3);
    float4 xv = reinterpret_cast<const float4*>(x)[(size_t)n * 8 + r];
    float4 pp = reinterpret_cast<const float4*>(b1)[r];
    float4 qq = make_float4(0.f, 0.f, 0.f, 0.f);
    matvec32(xv, w1, r, pp);
    matvec32(xv, w1 + HID * HID, r, qq);
    reinterpret_cast<float4*>(p)[(size_t)n * 8 + r] = pp;
    reinterpret_cast<float4*>(q)[(size_t)n * 8 + r] = qq;
}

// fused: CSR gather + relu-accum + (@W2 + deg*b2) + update MLP (+ optional output head)
__global__ void gather_update_kernel(float* __restrict__ x,
                                     const float* __restrict__ p,
                                     const float* __restrict__ q,
                                     const int2* __restrict__ recs,
                                     const int* __restrict__ off,
                                     const float* __restrict__ w1,   // for dist row (row 64)
                                     const float* __restrict__ w2,
                                     const float* __restrict__ b2,
                                     const float* __restrict__ uw1, const float* __restrict__ ub1,
                                     const float* __restrict__ uw2, const float* __restrict__ ub2,
                                     const float* __restrict__ ow,  const float* __restrict__ ob,
                                     float* __restrict__ fo) {
    int r = threadIdx.x & 7;
    int n = blockIdx.x * NPB4 + (threadIdx.x >> 3);
    int t0 = off[n];
    int t1 = (n == N_NODES - 1) ? N_EDGES : off[n + 1];

    const float4* q4 = reinterpret_cast<const float4*>(q);
    float4 pp = reinterpret_cast<const float4*>(p)[(size_t)n * 8 + r];
    float4 wd = reinterpret_cast<const float4*>(w1 + 2 * HID * HID)[r];  // dist row
    float4 rsum = make_float4(0.f, 0.f, 0.f, 0.f);

    for (int t = t0; t < t1; t += 8) {
        int m = t1 - t; if (m > 8) m = 8;   // uniform within the 8-lane group
        int2 rec = (r < m) ? recs[t + r] : make_int2(0, 0);
#pragma unroll
        for (int k = 0; k < 8; ++k) {
            int   s  = __shfl(rec.x, k, 8);
            float dt = __int_as_float(__shfl(rec.y, k, 8));
            float4 qv = q4[(size_t)s * 8 + r];   // 8 lanes -> one 128B row
            float c0 = fmaxf(fmaf(dt, wd.x, pp.x + qv.x), 0.0f);
            float c1 = fmaxf(fmaf(dt, wd.y, pp.y + qv.y), 0.0f);
            float c2 = fmaxf(fmaf(dt, wd.z, pp.z + qv.z), 0.0f);
            float c3 = fmaxf(fmaf(dt, wd.w, pp.w + qv.w), 0.0f);
            bool ok = (k < m);
            rsum.x += ok ? c0 : 0.0f;
            rsum.y += ok ? c1 : 0.0f;
            rsum.z += ok ? c2 : 0.0f;
            rsum.w += ok ? c3 : 0.0f;
        }
    }

    // agg = rsum @ W2 + deg * b2
    float deg = (float)(t1 - t0);
    float4 agg = reinterpret_cast<const float4*>(b2)[r];
    agg.x *= deg; agg.y *= deg; agg.z *= deg; agg.w *= deg;
    matvec32(rsum, w2, r, agg);

    // update MLP: h = relu([x, agg] @ uw1 + ub1); y = h @ uw2 + ub2
    float4 xv = reinterpret_cast<const float4*>(x)[(size_t)n * 8 + r];
    float4 h = reinterpret_cast<const float4*>(ub1)[r];
    matvec32(xv, uw1, r, h);
    matvec32(agg, uw1 + HID * HID, r, h);
    h = relu4(h);
    float4 y = reinterpret_cast<const float4*>(ub2)[r];
    matvec32(h, uw2, r, y);

    if (fo != nullptr) {
        // final layer: fuse output head, write to out
        float4 z = reinterpret_cast<const float4*>(ob)[r];
        matvec32(y, ow, r, z);
        reinterpret_cast<float4*>(fo)[(size_t)n * 8 + r] = z;
    } else {
        reinterpret_cast<float4*>(x)[(size_t)n * 8 + r] = y;
    }
}

// ---------------------------------------------------------------------------
extern "C" void kernel_launch(void* const* d_in, const int* in_sizes, int n_in,
                              void* d_out, int out_size, void* d_ws, size_t ws_size,
                              hipStream_t stream) {
    const float* node_feat = (const float*)d_in[0];
    const float* pos       = (const float*)d_in[1];
    const int*   ei        = (const int*)  d_in[2];   // int32 on device
    const float* enc_w1    = (const float*)d_in[3];
    const float* enc_b1    = (const float*)d_in[4];
    const float* enc_w2    = (const float*)d_in[5];
    const float* enc_b2    = (const float*)d_in[6];
    const float* msg_w1    = (const float*)d_in[7];   // [3, 65, 32]
    const float* msg_b1    = (const float*)d_in[8];
    const float* msg_w2    = (const float*)d_in[9];   // [3, 32, 32]
    const float* msg_b2    = (const float*)d_in[10];
    const float* upd_w1    = (const float*)d_in[11];  // [3, 64, 32]
    const float* upd_b1    = (const float*)d_in[12];
    const float* upd_w2    = (const float*)d_in[13];
    const float* upd_b2    = (const float*)d_in[14];
    const float* out_w     = (const float*)d_in[15];
    const float* out_b     = (const float*)d_in[16];
    float* out = (float*)d_out;

    // workspace layout (4-byte elements), ~58.4 MB total
    char* ws = (char*)d_ws;
    float* x      = (float*)ws;                                   // N*32
    float* p      = x + (size_t)N_NODES * HID;                    // N*32
    float* q      = p + (size_t)N_NODES * HID;                    // N*32
    int2*  recs   = (int2*)(q + (size_t)N_NODES * HID);           // E (8B each)
    int*   rank   = (int*)(recs + (size_t)N_EDGES);               // E
    int*   cnt    = rank + (size_t)N_EDGES;                       // N
    int*   off    = cnt + N_NODES;                                // N+1 (off[N] unused)
    int*   bsum   = off + (N_NODES + 1);                          // <=256
    int*   boff   = bsum + 256;                                   // <=256

    const int B = 256;
    const int gridE = (N_EDGES + B - 1) / B;
    const int NB = (N_NODES + SCAN_B - 1) / SCAN_B;               // 98

    // ---- build CSR (once per launch) ----
    zero_int_kernel<<<(N_NODES + B - 1) / B, B, 0, stream>>>(cnt, N_NODES);
    rank_kernel<<<gridE, B, 0, stream>>>(ei, cnt, rank);
    scan1_kernel<<<NB, 256, 0, stream>>>(cnt, off, bsum);
    scan2_kernel<<<1, 256, 0, stream>>>(bsum, boff, NB);
    scan3_kernel<<<(N_NODES + B - 1) / B, B, 0, stream>>>(off, boff);
    scatter_kernel<<<gridE, B, 0, stream>>>(ei, pos, off, rank, recs);

    // ---- model (8 lanes per node; 32 nodes per block) ----
    encoder_kernel<<<GRID4, B, 0, stream>>>(node_feat, enc_w1, enc_b1, enc_w2, enc_b2, x);

    for (int l = 0; l < NUM_LAYERS; ++l) {
        const float* w1 = msg_w1 + (size_t)l * (2 * HID + 1) * HID;
        bool last = (l == NUM_LAYERS - 1);
        proj_kernel<<<GRID4, B, 0, stream>>>(x, w1, msg_b1 + (size_t)l * HID, p, q);
        gather_update_kernel<<<GRID4, B, 0, stream>>>(
            x, p, q, recs, off,
            w1,
            msg_w2 + (size_t)l * HID * HID,
            msg_b2 + (size_t)l * HID,
            upd_w1 + (size_t)l * (2 * HID) * HID,
            upd_b1 + (size_t)l * HID,
            upd_w2 + (size_t)l * HID * HID,
            upd_b2 + (size_t)l * HID,
            last ? out_w : nullptr,
            last ? out_b : nullptr,
            last ? out : nullptr);
    }
}